// Round 17
// baseline (282.105 us; speedup 1.0000x reference)
//
#include <hip/hip_runtime.h>
#include <stdint.h>

// Problem constants: B=2, L=2048, D=1024, H=16, HD=64
#define SCALE_ 0.125f

typedef unsigned short u16;
typedef __attribute__((ext_vector_type(8))) __bf16 bf16x8;
typedef __attribute__((ext_vector_type(4))) float f32x4;
typedef __attribute__((ext_vector_type(4))) unsigned int u32x4;

__device__ __forceinline__ void gload16(const void* g, void* l) {
  __builtin_amdgcn_global_load_lds(
      (const __attribute__((address_space(1))) unsigned int*)g,
      (__attribute__((address_space(3))) unsigned int*)l, 16, 0, 0);
}

__device__ __forceinline__ u16 f2bf(float f) {
  union { float f; unsigned int u; } v; v.f = f;
  return (u16)((v.u + 0x7FFFu + ((v.u >> 16) & 1u)) >> 16);
}

__device__ __forceinline__ bf16x8 ld_bf8(const u16* p) {
  return *reinterpret_cast<const bf16x8*>(p);
}

// ---------------- fused: fp32->bf16 cvt (x + 4 weights) AND mask zero-scan ---
// Grid MUST be 8192: blocks 0..4095 convert 8,388,608 elements (x + 4 W);
// blocks 4096..8191 scan the 2*2048*2048 = 8,388,608-float mask (8/thread).
__global__ __launch_bounds__(256) void cvt_scan_kernel(
    const float* __restrict__ x, const float* __restrict__ wq,
    const float* __restrict__ wk, const float* __restrict__ wv,
    const float* __restrict__ wo, u16* __restrict__ ws,
    const float* __restrict__ mask, int* __restrict__ flag) {
  if (blockIdx.x >= 4096) {
    const long i = ((long)(blockIdx.x - 4096) * 256 + threadIdx.x) * 8;
    const u32x4 a = *(const u32x4*)(mask + i);
    const u32x4 b = *(const u32x4*)(mask + i + 4);
    const unsigned int v = a[0] | a[1] | a[2] | a[3] | b[0] | b[1] | b[2] | b[3];
    if (__any(v != 0)) {
      if ((threadIdx.x & 63) == 0) atomicOr(flag, 1);
    }
    return;
  }
  long e0 = ((long)blockIdx.x * 256 + threadIdx.x) * 8;
  const float* src; u16* dst; long off;
  if (e0 < 4194304L) {
    src = x; dst = ws; off = e0;
  } else {
    long tt = e0 - 4194304L;
    int w = (int)(tt >> 20);
    off = tt & 1048575L;
    src = (w == 0) ? wq : (w == 1) ? wk : (w == 2) ? wv : wo;
    dst = ws + 4194304L + (long)w * 1048576L;
  }
  float4 f0 = *(const float4*)(src + off);
  float4 f1 = *(const float4*)(src + off + 4);
  union { u16 u[8]; u32x4 v; } r;
  r.u[0] = f2bf(f0.x); r.u[1] = f2bf(f0.y); r.u[2] = f2bf(f0.z); r.u[3] = f2bf(f0.w);
  r.u[4] = f2bf(f1.x); r.u[5] = f2bf(f1.y); r.u[6] = f2bf(f1.z); r.u[7] = f2bf(f1.w);
  *reinterpret_cast<u32x4*>(dst + off) = r.v;
}

// ---------------- GEMM: C[m][n] = sum_k A[m][k] * W[n][k] -------------------
// 128x128 tile, BK=32. mode 0: Q(B,H,L,HD)*SCALE  1: K(B,H,L,HD)  2: V->(B,H,HD,L)
__global__ __launch_bounds__(256) void gemm_bt(
    const u16* __restrict__ A,
    const u16* __restrict__ W0, const u16* __restrict__ W1, const u16* __restrict__ W2,
    const float* __restrict__ b0, const float* __restrict__ b1, const float* __restrict__ b2,
    void* __restrict__ d0, void* __restrict__ d1, void* __restrict__ d2,
    int mode_base) {
  __shared__ u16 lsA[128 * 32];
  __shared__ u16 lsB[128 * 32];

  const int z = blockIdx.z;
  const int mode = mode_base + z;
  const u16* W = (z == 0) ? W0 : (z == 1) ? W1 : W2;
  const float* bias = (z == 0) ? b0 : (z == 1) ? b1 : b2;
  void* dst = (z == 0) ? d0 : (z == 1) ? d1 : d2;
  const float scale = (mode == 0) ? SCALE_ : 1.0f;

  const int t = threadIdx.x;
  const int bm = blockIdx.y, bn = blockIdx.x;
  const int lane = t & 63, lr = lane & 15, lg = lane >> 4;
  const int wid = t >> 6, wr = wid >> 1, wc = wid & 1;

  f32x4 zero = {0.f, 0.f, 0.f, 0.f};
  f32x4 acc[4][4];
#pragma unroll
  for (int i = 0; i < 4; ++i)
#pragma unroll
    for (int j = 0; j < 4; ++j) acc[i][j] = zero;

  const u16* gA = A + (size_t)(bm * 128) * 1024;
  const u16* gB = W + (size_t)(bn * 128) * 1024;
  const int srow = t >> 2, scol = (t & 3) * 8;

  for (int kt = 0; kt < 32; ++kt) {
    const int k0 = kt * 32;
    __syncthreads();
    gload16(gA + (size_t)srow * 1024 + k0 + scol,        &lsA[t * 8]);
    gload16(gA + (size_t)(srow + 64) * 1024 + k0 + scol, &lsA[2048 + t * 8]);
    gload16(gB + (size_t)srow * 1024 + k0 + scol,        &lsB[t * 8]);
    gload16(gB + (size_t)(srow + 64) * 1024 + k0 + scol, &lsB[2048 + t * 8]);
    __syncthreads();

    bf16x8 af[4], bf[4];
#pragma unroll
    for (int mi = 0; mi < 4; ++mi)
      af[mi] = ld_bf8(&lsA[(wr * 64 + mi * 16 + lr) * 32 + lg * 8]);
#pragma unroll
    for (int ni = 0; ni < 4; ++ni)
      bf[ni] = ld_bf8(&lsB[(wc * 64 + ni * 16 + lr) * 32 + lg * 8]);
#pragma unroll
    for (int mi = 0; mi < 4; ++mi)
#pragma unroll
      for (int ni = 0; ni < 4; ++ni)
        acc[mi][ni] = __builtin_amdgcn_mfma_f32_16x16x32_bf16(af[mi], bf[ni], acc[mi][ni], 0, 0, 0);
  }

#pragma unroll
  for (int ni = 0; ni < 4; ++ni) {
    const int gcol = bn * 128 + wc * 64 + ni * 16 + lr;
    const float bv = bias[gcol];
#pragma unroll
    for (int mi = 0; mi < 4; ++mi) {
      const int growb = bm * 128 + wr * 64 + mi * 16 + lg * 4;
#pragma unroll
      for (int j = 0; j < 4; ++j) {
        const int grow = growb + j;
        const float val = (acc[mi][ni][j] + bv) * scale;
        if (mode == 3) {
          ((float*)dst)[(size_t)grow * 1024 + gcol] = val;
        } else {
          const int b = grow >> 11, l = grow & 2047, h = gcol >> 6, hd = gcol & 63;
          size_t idx;
          if (mode == 2) idx = (((size_t)(b * 16 + h)) * 64 + hd) * 2048 + l;
          else           idx = (((size_t)(b * 16 + h)) * 2048 + l) * 64 + hd;
          ((u16*)dst)[idx] = f2bf(val);
        }
      }
    }
  }
}

// ---------------- out-proj GEMM, 64x128 tile (512 blocks -> 2 blocks/CU) ----
__global__ __launch_bounds__(256) void gemm_out64(
    const u16* __restrict__ A, const u16* __restrict__ W,
    const float* __restrict__ bias, float* __restrict__ out) {
  __shared__ u16 lsA[64 * 32];
  __shared__ u16 lsB[128 * 32];

  const int t = threadIdx.x;
  const int bm = blockIdx.y, bn = blockIdx.x;
  const int lane = t & 63, lr = lane & 15, lg = lane >> 4;
  const int wid = t >> 6;

  f32x4 zero = {0.f, 0.f, 0.f, 0.f};
  f32x4 acc[4][2];
#pragma unroll
  for (int i = 0; i < 4; ++i) { acc[i][0] = zero; acc[i][1] = zero; }

  const u16* gA = A + (size_t)(bm * 64) * 1024;
  const u16* gB = W + (size_t)(bn * 128) * 1024;
  const int srow = t >> 2, scol = (t & 3) * 8;

  for (int kt = 0; kt < 32; ++kt) {
    const int k0 = kt * 32;
    __syncthreads();
    gload16(gA + (size_t)srow * 1024 + k0 + scol,        &lsA[t * 8]);
    gload16(gB + (size_t)srow * 1024 + k0 + scol,        &lsB[t * 8]);
    gload16(gB + (size_t)(srow + 64) * 1024 + k0 + scol, &lsB[2048 + t * 8]);
    __syncthreads();

    bf16x8 af[4], bf[2];
#pragma unroll
    for (int mi = 0; mi < 4; ++mi)
      af[mi] = ld_bf8(&lsA[(mi * 16 + lr) * 32 + lg * 8]);
#pragma unroll
    for (int ni = 0; ni < 2; ++ni)
      bf[ni] = ld_bf8(&lsB[(wid * 32 + ni * 16 + lr) * 32 + lg * 8]);
#pragma unroll
    for (int mi = 0; mi < 4; ++mi)
#pragma unroll
      for (int ni = 0; ni < 2; ++ni)
        acc[mi][ni] = __builtin_amdgcn_mfma_f32_16x16x32_bf16(af[mi], bf[ni], acc[mi][ni], 0, 0, 0);
  }

#pragma unroll
  for (int ni = 0; ni < 2; ++ni) {
    const int gcol = bn * 128 + wid * 32 + ni * 16 + lr;
    const float bv = bias[gcol];
#pragma unroll
    for (int mi = 0; mi < 4; ++mi) {
      const int growb = bm * 64 + mi * 16 + lg * 4;
#pragma unroll
      for (int j = 0; j < 4; ++j)
        out[(size_t)(growb + j) * 1024 + gcol] = acc[mi][ni][j] + bv;
    }
  }
}

// ---------------- flash attention (R16 + 1KB bias bursts, unroll x4) ---------
// Q,K: (B,H,L,64) bf16 (Q pre-scaled). Vt: (B,H,64,L) bf16.
// kt-loop unrolled x4: first sub-iter loads bias for 256 cols (16 sequential
// 64B lines per row = 1KB bursts) into bbw[4][16]; three following sub-iters
// consume held registers with ZERO bias loads (up to 3 iters of slack).
// Confirmed-axis extension of R16's 512B-burst win (-21us). All else as R16.
__global__ __launch_bounds__(256, 4) void attn_kernel(
    const u16* __restrict__ Q, const u16* __restrict__ Kb_, const u16* __restrict__ Vtb,
    const float* __restrict__ bias, const float* __restrict__ mask,
    const int* __restrict__ mz, u16* __restrict__ attn) {
  __shared__ u16 lsK[64 * 64];      // [krow][hd], swizzled
  __shared__ u16 lsV[64 * 64];      // [hd][k],   swizzled
  __shared__ u16 lsP[4][16 * 88];   // per-wave P, row stride 88

  const int t = threadIdx.x, wid = t >> 6, lane = t & 63, lr = lane & 15, lg = lane >> 4;

  // XCD-chunked decode: 1024 blocks = 8 xcd x (4 bh x 32 qt)
  const int id = blockIdx.x;
  const int idx = id >> 3;
  const int bh = (id & 7) * 4 + (idx >> 5);
  const int qt = idx & 31;
  const int b = bh >> 4, h = bh & 15;
  const int q0 = qt * 64;

  const bool usemask = (*mz) != 0;   // uniform across all waves

  const u16* qb = Q + ((size_t)bh * 2048 + q0 + wid * 16) * 64;
  const u16* kb = Kb_ + (size_t)bh * 2048 * 64;
  const u16* vb = Vtb + (size_t)bh * 64 * 2048;
  const float* biasr = bias + (size_t)bh * 2048 * 2048;
  const float* maskr = mask + (size_t)b * 2048 * 2048;

  bf16x8 qf[2];
  qf[0] = ld_bf8(qb + (size_t)lr * 64 + lg * 8);
  qf[1] = ld_bf8(qb + (size_t)lr * 64 + 32 + lg * 8);

  float lsum[4] = {0.f, 0.f, 0.f, 0.f};
  f32x4 zero = {0.f, 0.f, 0.f, 0.f};
  f32x4 o[4];
#pragma unroll
  for (int i = 0; i < 4; ++i) o[i] = zero;

  const int srow = t >> 3;
  const int swz = ((t & 7) ^ (srow & 7)) * 8;  // pre-swizzled source chunk
  const int rsw = (lr & 7) * 8;                // read-side XOR (u16 units)
  const int qrow0 = q0 + wid * 16 + lg * 4;

  float bbw[4][16];                  // bias+mask for 256 cols (4 sub-iters)

  // one sub-iteration: stage K/V at K0_, compute using bbw[][NOFS..NOFS+3]
#define SUBITER(K0_, NOFS, LOADB)                                              \
  {                                                                            \
    const int k0s = (K0_);                                                     \
    __syncthreads();                                                           \
    gload16(kb + (size_t)(k0s + srow) * 64 + swz,        &lsK[t * 8]);         \
    gload16(kb + (size_t)(k0s + srow + 32) * 64 + swz,   &lsK[2048 + t * 8]);  \
    gload16(vb + (size_t)srow * 2048 + k0s + swz,        &lsV[t * 8]);         \
    gload16(vb + (size_t)(srow + 32) * 2048 + k0s + swz, &lsV[2048 + t * 8]);  \
    if (LOADB) {                                                               \
      _Pragma("unroll")                                                        \
      for (int j = 0; j < 4; ++j) {                                            \
        const float* br = biasr + (size_t)(qrow0 + j) * 2048 + k0s + lr;       \
        _Pragma("unroll")                                                      \
        for (int n = 0; n < 16; ++n) bbw[j][n] = br[n * 16];                   \
      }                                                                        \
      if (usemask) {                                                           \
        _Pragma("unroll")                                                      \
        for (int j = 0; j < 4; ++j) {                                          \
          const float* mr = maskr + (size_t)(qrow0 + j) * 2048 + k0s + lr;     \
          _Pragma("unroll")                                                    \
          for (int n = 0; n < 16; ++n) bbw[j][n] += mr[n * 16];                \
        }                                                                      \
      }                                                                        \
    }                                                                          \
    __syncthreads();                                                           \
    f32x4 s[4];                                                                \
    _Pragma("unroll")                                                          \
    for (int n = 0; n < 4; ++n) s[n] = zero;                                   \
    __builtin_amdgcn_s_setprio(1);                                             \
    _Pragma("unroll")                                                          \
    for (int ks = 0; ks < 2; ++ks)                                             \
      _Pragma("unroll")                                                        \
      for (int n = 0; n < 4; ++n) {                                            \
        bf16x8 kf = ld_bf8(&lsK[((n * 16 + lr) * 64 + ks * 32 + lg * 8) ^ rsw]);\
        s[n] = __builtin_amdgcn_mfma_f32_16x16x32_bf16(qf[ks], kf, s[n], 0, 0, 0);\
      }                                                                        \
    __builtin_amdgcn_s_setprio(0);                                             \
    _Pragma("unroll")                                                          \
    for (int i = 0; i < 4; ++i) {                                              \
      float rs = 0.f;                                                          \
      _Pragma("unroll")                                                        \
      for (int n = 0; n < 4; ++n) {                                            \
        float p = __expf(s[n][i] + bbw[i][(NOFS) + n]);                        \
        s[n][i] = p;                                                           \
        rs += p;                                                               \
      }                                                                        \
      lsum[i] += rs;                                                           \
    }                                                                          \
    _Pragma("unroll")                                                          \
    for (int n = 0; n < 4; ++n)                                                \
      _Pragma("unroll")                                                        \
      for (int i = 0; i < 4; ++i)                                              \
        lsP[wid][(lg * 4 + i) * 88 + n * 16 + lr] = f2bf(s[n][i]);             \
    asm volatile("s_waitcnt lgkmcnt(0)" ::: "memory");                         \
    __builtin_amdgcn_sched_barrier(0);                                         \
    __builtin_amdgcn_s_setprio(1);                                             \
    _Pragma("unroll")                                                          \
    for (int ks = 0; ks < 2; ++ks) {                                           \
      bf16x8 pa = ld_bf8(&lsP[wid][lr * 88 + ks * 32 + lg * 8]);               \
      _Pragma("unroll")                                                        \
      for (int dt = 0; dt < 4; ++dt) {                                         \
        bf16x8 vf = ld_bf8(&lsV[((dt * 16 + lr) * 64 + ks * 32 + lg * 8) ^ rsw]);\
        o[dt] = __builtin_amdgcn_mfma_f32_16x16x32_bf16(pa, vf, o[dt], 0, 0, 0);\
      }                                                                        \
    }                                                                          \
    __builtin_amdgcn_s_setprio(0);                                             \
  }

  for (int kt4 = 0; kt4 < 8; ++kt4) {
    const int k0 = kt4 * 256;
    SUBITER(k0, 0, 1);          // loads 256 cols of bias (1KB bursts/row)
    SUBITER(k0 + 64, 4, 0);
    SUBITER(k0 + 128, 8, 0);
    SUBITER(k0 + 192, 12, 0);
  }
#undef SUBITER

  // epilogue: single 16-lane reduce of lsum partials, then write
#pragma unroll
  for (int i = 0; i < 4; ++i) {
    lsum[i] += __shfl_xor(lsum[i], 1);
    lsum[i] += __shfl_xor(lsum[i], 2);
    lsum[i] += __shfl_xor(lsum[i], 4);
    lsum[i] += __shfl_xor(lsum[i], 8);
  }
  float inv[4];
#pragma unroll
  for (int i = 0; i < 4; ++i) inv[i] = 1.0f / lsum[i];
#pragma unroll
  for (int dt = 0; dt < 4; ++dt) {
    const int dcol = h * 64 + dt * 16 + lr;
#pragma unroll
    for (int i = 0; i < 4; ++i)
      attn[((size_t)b * 2048 + qrow0 + i) * 1024 + dcol] = f2bf(o[dt][i] * inv[i]);
  }
}

// ---------------- launch ------------------------------------------------------
extern "C" void kernel_launch(void* const* d_in, const int* in_sizes, int n_in,
                              void* d_out, int out_size, void* d_ws, size_t ws_size,
                              hipStream_t stream) {
  const float* x    = (const float*)d_in[0];
  const float* bias = (const float*)d_in[1];
  const float* mask = (const float*)d_in[2];
  const float* Wq   = (const float*)d_in[3];
  const float* bq   = (const float*)d_in[4];
  const float* Wk   = (const float*)d_in[5];
  const float* bk   = (const float*)d_in[6];
  const float* Wv   = (const float*)d_in[7];
  const float* bv   = (const float*)d_in[8];
  const float* Wo   = (const float*)d_in[9];
  const float* bo   = (const float*)d_in[10];
  float* out = (float*)d_out;

  u16* ws   = (u16*)d_ws;
  u16* xb   = ws;                    // 4194304
  u16* wqb  = ws + 4194304L;         // 1048576
  u16* wkb  = wqb + 1048576L;
  u16* wvb  = wkb + 1048576L;
  u16* wob  = wvb + 1048576L;
  u16* Qb   = wob + 1048576L;        // 4194304 (B,H,L,HD)
  u16* Kb   = Qb + 4194304L;         // 4194304
  u16* Vtb  = Kb + 4194304L;         // 4194304 (B,H,HD,L)
  u16* attnb = Vtb + 4194304L;       // 4194304 (B,L,D)
  int* mzflag = (int*)(attnb + 4194304L);

  hipMemsetAsync(mzflag, 0, 4, stream);
  cvt_scan_kernel<<<8192, 256, 0, stream>>>(x, Wq, Wk, Wv, Wo, ws, mask, mzflag);

  dim3 gqkv(8, 32, 3);
  gemm_bt<<<gqkv, 256, 0, stream>>>(xb, wqb, wkb, wvb, bq, bk, bv,
                                    (void*)Qb, (void*)Kb, (void*)Vtb, 0);

  attn_kernel<<<dim3(1024), 256, 0, stream>>>(Qb, Kb, Vtb, bias, mask, mzflag, attnb);

  gemm_out64<<<dim3(8, 64), 256, 0, stream>>>(attnb, wob, bo, out);
}

// Round 18
// 202.360 us; speedup vs baseline: 1.3941x; 1.3941x over previous
//
#include <hip/hip_runtime.h>
#include <stdint.h>

// Problem constants: B=2, L=2048, D=1024, H=16, HD=64
#define SCALE_ 0.125f

typedef unsigned short u16;
typedef __attribute__((ext_vector_type(8))) __bf16 bf16x8;
typedef __attribute__((ext_vector_type(4))) float f32x4;
typedef __attribute__((ext_vector_type(4))) unsigned int u32x4;

__device__ __forceinline__ void gload16(const void* g, void* l) {
  __builtin_amdgcn_global_load_lds(
      (const __attribute__((address_space(1))) unsigned int*)g,
      (__attribute__((address_space(3))) unsigned int*)l, 16, 0, 0);
}

__device__ __forceinline__ u16 f2bf(float f) {
  union { float f; unsigned int u; } v; v.f = f;
  return (u16)((v.u + 0x7FFFu + ((v.u >> 16) & 1u)) >> 16);
}

__device__ __forceinline__ bf16x8 ld_bf8(const u16* p) {
  return *reinterpret_cast<const bf16x8*>(p);
}

// ---------------- fused: fp32->bf16 cvt (x + 4 weights) AND mask zero-scan ---
// Grid MUST be 8192: blocks 0..4095 convert 8,388,608 elements (x + 4 W);
// blocks 4096..8191 scan the 2*2048*2048 = 8,388,608-float mask (8/thread).
__global__ __launch_bounds__(256) void cvt_scan_kernel(
    const float* __restrict__ x, const float* __restrict__ wq,
    const float* __restrict__ wk, const float* __restrict__ wv,
    const float* __restrict__ wo, u16* __restrict__ ws,
    const float* __restrict__ mask, int* __restrict__ flag) {
  if (blockIdx.x >= 4096) {
    const long i = ((long)(blockIdx.x - 4096) * 256 + threadIdx.x) * 8;
    const u32x4 a = *(const u32x4*)(mask + i);
    const u32x4 b = *(const u32x4*)(mask + i + 4);
    const unsigned int v = a[0] | a[1] | a[2] | a[3] | b[0] | b[1] | b[2] | b[3];
    if (__any(v != 0)) {
      if ((threadIdx.x & 63) == 0) atomicOr(flag, 1);
    }
    return;
  }
  long e0 = ((long)blockIdx.x * 256 + threadIdx.x) * 8;
  const float* src; u16* dst; long off;
  if (e0 < 4194304L) {
    src = x; dst = ws; off = e0;
  } else {
    long tt = e0 - 4194304L;
    int w = (int)(tt >> 20);
    off = tt & 1048575L;
    src = (w == 0) ? wq : (w == 1) ? wk : (w == 2) ? wv : wo;
    dst = ws + 4194304L + (long)w * 1048576L;
  }
  float4 f0 = *(const float4*)(src + off);
  float4 f1 = *(const float4*)(src + off + 4);
  union { u16 u[8]; u32x4 v; } r;
  r.u[0] = f2bf(f0.x); r.u[1] = f2bf(f0.y); r.u[2] = f2bf(f0.z); r.u[3] = f2bf(f0.w);
  r.u[4] = f2bf(f1.x); r.u[5] = f2bf(f1.y); r.u[6] = f2bf(f1.z); r.u[7] = f2bf(f1.w);
  *reinterpret_cast<u32x4*>(dst + off) = r.v;
}

// ---------------- GEMM: C[m][n] = sum_k A[m][k] * W[n][k] -------------------
// 128x128 tile, BK=32. mode 0: Q(B,H,L,HD)*SCALE  1: K(B,H,L,HD)  2: V->(B,H,HD,L)
__global__ __launch_bounds__(256) void gemm_bt(
    const u16* __restrict__ A,
    const u16* __restrict__ W0, const u16* __restrict__ W1, const u16* __restrict__ W2,
    const float* __restrict__ b0, const float* __restrict__ b1, const float* __restrict__ b2,
    void* __restrict__ d0, void* __restrict__ d1, void* __restrict__ d2,
    int mode_base) {
  __shared__ u16 lsA[128 * 32];
  __shared__ u16 lsB[128 * 32];

  const int z = blockIdx.z;
  const int mode = mode_base + z;
  const u16* W = (z == 0) ? W0 : (z == 1) ? W1 : W2;
  const float* bias = (z == 0) ? b0 : (z == 1) ? b1 : b2;
  void* dst = (z == 0) ? d0 : (z == 1) ? d1 : d2;
  const float scale = (mode == 0) ? SCALE_ : 1.0f;

  const int t = threadIdx.x;
  const int bm = blockIdx.y, bn = blockIdx.x;
  const int lane = t & 63, lr = lane & 15, lg = lane >> 4;
  const int wid = t >> 6, wr = wid >> 1, wc = wid & 1;

  f32x4 zero = {0.f, 0.f, 0.f, 0.f};
  f32x4 acc[4][4];
#pragma unroll
  for (int i = 0; i < 4; ++i)
#pragma unroll
    for (int j = 0; j < 4; ++j) acc[i][j] = zero;

  const u16* gA = A + (size_t)(bm * 128) * 1024;
  const u16* gB = W + (size_t)(bn * 128) * 1024;
  const int srow = t >> 2, scol = (t & 3) * 8;

  for (int kt = 0; kt < 32; ++kt) {
    const int k0 = kt * 32;
    __syncthreads();
    gload16(gA + (size_t)srow * 1024 + k0 + scol,        &lsA[t * 8]);
    gload16(gA + (size_t)(srow + 64) * 1024 + k0 + scol, &lsA[2048 + t * 8]);
    gload16(gB + (size_t)srow * 1024 + k0 + scol,        &lsB[t * 8]);
    gload16(gB + (size_t)(srow + 64) * 1024 + k0 + scol, &lsB[2048 + t * 8]);
    __syncthreads();

    bf16x8 af[4], bf[4];
#pragma unroll
    for (int mi = 0; mi < 4; ++mi)
      af[mi] = ld_bf8(&lsA[(wr * 64 + mi * 16 + lr) * 32 + lg * 8]);
#pragma unroll
    for (int ni = 0; ni < 4; ++ni)
      bf[ni] = ld_bf8(&lsB[(wc * 64 + ni * 16 + lr) * 32 + lg * 8]);
#pragma unroll
    for (int mi = 0; mi < 4; ++mi)
#pragma unroll
      for (int ni = 0; ni < 4; ++ni)
        acc[mi][ni] = __builtin_amdgcn_mfma_f32_16x16x32_bf16(af[mi], bf[ni], acc[mi][ni], 0, 0, 0);
  }

#pragma unroll
  for (int ni = 0; ni < 4; ++ni) {
    const int gcol = bn * 128 + wc * 64 + ni * 16 + lr;
    const float bv = bias[gcol];
#pragma unroll
    for (int mi = 0; mi < 4; ++mi) {
      const int growb = bm * 128 + wr * 64 + mi * 16 + lg * 4;
#pragma unroll
      for (int j = 0; j < 4; ++j) {
        const int grow = growb + j;
        const float val = (acc[mi][ni][j] + bv) * scale;
        if (mode == 3) {
          ((float*)dst)[(size_t)grow * 1024 + gcol] = val;
        } else {
          const int b = grow >> 11, l = grow & 2047, h = gcol >> 6, hd = gcol & 63;
          size_t idx;
          if (mode == 2) idx = (((size_t)(b * 16 + h)) * 64 + hd) * 2048 + l;
          else           idx = (((size_t)(b * 16 + h)) * 2048 + l) * 64 + hd;
          ((u16*)dst)[idx] = f2bf(val);
        }
      }
    }
  }
}

// ---------------- out-proj GEMM, 64x128 tile (512 blocks -> 2 blocks/CU) ----
__global__ __launch_bounds__(256) void gemm_out64(
    const u16* __restrict__ A, const u16* __restrict__ W,
    const float* __restrict__ bias, float* __restrict__ out) {
  __shared__ u16 lsA[64 * 32];
  __shared__ u16 lsB[128 * 32];

  const int t = threadIdx.x;
  const int bm = blockIdx.y, bn = blockIdx.x;
  const int lane = t & 63, lr = lane & 15, lg = lane >> 4;
  const int wid = t >> 6;

  f32x4 zero = {0.f, 0.f, 0.f, 0.f};
  f32x4 acc[4][2];
#pragma unroll
  for (int i = 0; i < 4; ++i) { acc[i][0] = zero; acc[i][1] = zero; }

  const u16* gA = A + (size_t)(bm * 64) * 1024;
  const u16* gB = W + (size_t)(bn * 128) * 1024;
  const int srow = t >> 2, scol = (t & 3) * 8;

  for (int kt = 0; kt < 32; ++kt) {
    const int k0 = kt * 32;
    __syncthreads();
    gload16(gA + (size_t)srow * 1024 + k0 + scol,        &lsA[t * 8]);
    gload16(gB + (size_t)srow * 1024 + k0 + scol,        &lsB[t * 8]);
    gload16(gB + (size_t)(srow + 64) * 1024 + k0 + scol, &lsB[2048 + t * 8]);
    __syncthreads();

    bf16x8 af[4], bf[2];
#pragma unroll
    for (int mi = 0; mi < 4; ++mi)
      af[mi] = ld_bf8(&lsA[(mi * 16 + lr) * 32 + lg * 8]);
#pragma unroll
    for (int ni = 0; ni < 2; ++ni)
      bf[ni] = ld_bf8(&lsB[(wid * 32 + ni * 16 + lr) * 32 + lg * 8]);
#pragma unroll
    for (int mi = 0; mi < 4; ++mi)
#pragma unroll
      for (int ni = 0; ni < 2; ++ni)
        acc[mi][ni] = __builtin_amdgcn_mfma_f32_16x16x32_bf16(af[mi], bf[ni], acc[mi][ni], 0, 0, 0);
  }

#pragma unroll
  for (int ni = 0; ni < 2; ++ni) {
    const int gcol = bn * 128 + wid * 32 + ni * 16 + lr;
    const float bv = bias[gcol];
#pragma unroll
    for (int mi = 0; mi < 4; ++mi) {
      const int growb = bm * 64 + mi * 16 + lg * 4;
#pragma unroll
      for (int j = 0; j < 4; ++j)
        out[(size_t)(growb + j) * 1024 + gcol] = acc[mi][ni][j] + bv;
    }
  }
}

// ---------------- flash attention (R16 exact: 512B bias bursts, unroll x2) ---
// Q,K: (B,H,L,64) bf16 (Q pre-scaled). Vt: (B,H,64,L) bf16.
// kt-loop unrolled x2: even sub-iter loads bias for 128 cols (8 sequential
// 64B lines per row = 512B bursts) into bbw[4][8]; odd sub-iter consumes the
// held upper half with ZERO bias loads (full extra iteration of slack).
// 1KB bursts (x4 unroll) REFUTED in R17: bbw[4][16] spills at (256,4).
__global__ __launch_bounds__(256, 4) void attn_kernel(
    const u16* __restrict__ Q, const u16* __restrict__ Kb_, const u16* __restrict__ Vtb,
    const float* __restrict__ bias, const float* __restrict__ mask,
    const int* __restrict__ mz, u16* __restrict__ attn) {
  __shared__ u16 lsK[64 * 64];      // [krow][hd], swizzled
  __shared__ u16 lsV[64 * 64];      // [hd][k],   swizzled
  __shared__ u16 lsP[4][16 * 88];   // per-wave P, row stride 88

  const int t = threadIdx.x, wid = t >> 6, lane = t & 63, lr = lane & 15, lg = lane >> 4;

  // XCD-chunked decode: 1024 blocks = 8 xcd x (4 bh x 32 qt)
  const int id = blockIdx.x;
  const int idx = id >> 3;
  const int bh = (id & 7) * 4 + (idx >> 5);
  const int qt = idx & 31;
  const int b = bh >> 4, h = bh & 15;
  const int q0 = qt * 64;

  const bool usemask = (*mz) != 0;   // uniform across all waves

  const u16* qb = Q + ((size_t)bh * 2048 + q0 + wid * 16) * 64;
  const u16* kb = Kb_ + (size_t)bh * 2048 * 64;
  const u16* vb = Vtb + (size_t)bh * 64 * 2048;
  const float* biasr = bias + (size_t)bh * 2048 * 2048;
  const float* maskr = mask + (size_t)b * 2048 * 2048;

  bf16x8 qf[2];
  qf[0] = ld_bf8(qb + (size_t)lr * 64 + lg * 8);
  qf[1] = ld_bf8(qb + (size_t)lr * 64 + 32 + lg * 8);

  float lsum[4] = {0.f, 0.f, 0.f, 0.f};
  f32x4 zero = {0.f, 0.f, 0.f, 0.f};
  f32x4 o[4];
#pragma unroll
  for (int i = 0; i < 4; ++i) o[i] = zero;

  const int srow = t >> 3;
  const int swz = ((t & 7) ^ (srow & 7)) * 8;  // pre-swizzled source chunk
  const int rsw = (lr & 7) * 8;                // read-side XOR (u16 units)
  const int qrow0 = q0 + wid * 16 + lg * 4;

  float bbw[4][8];                   // bias+mask for 128 cols (2 sub-iters)

  // one sub-iteration: stage K/V at K0_, compute using bbw[][NOFS..NOFS+3]
#define SUBITER(K0_, NOFS, LOADB)                                              \
  {                                                                            \
    const int k0s = (K0_);                                                     \
    __syncthreads();                                                           \
    gload16(kb + (size_t)(k0s + srow) * 64 + swz,        &lsK[t * 8]);         \
    gload16(kb + (size_t)(k0s + srow + 32) * 64 + swz,   &lsK[2048 + t * 8]);  \
    gload16(vb + (size_t)srow * 2048 + k0s + swz,        &lsV[t * 8]);         \
    gload16(vb + (size_t)(srow + 32) * 2048 + k0s + swz, &lsV[2048 + t * 8]);  \
    if (LOADB) {                                                               \
      _Pragma("unroll")                                                        \
      for (int j = 0; j < 4; ++j) {                                            \
        const float* br = biasr + (size_t)(qrow0 + j) * 2048 + k0s + lr;       \
        _Pragma("unroll")                                                      \
        for (int n = 0; n < 8; ++n) bbw[j][n] = br[n * 16];                    \
      }                                                                        \
      if (usemask) {                                                           \
        _Pragma("unroll")                                                      \
        for (int j = 0; j < 4; ++j) {                                          \
          const float* mr = maskr + (size_t)(qrow0 + j) * 2048 + k0s + lr;     \
          _Pragma("unroll")                                                    \
          for (int n = 0; n < 8; ++n) bbw[j][n] += mr[n * 16];                 \
        }                                                                      \
      }                                                                        \
    }                                                                          \
    __syncthreads();                                                           \
    f32x4 s[4];                                                                \
    _Pragma("unroll")                                                          \
    for (int n = 0; n < 4; ++n) s[n] = zero;                                   \
    __builtin_amdgcn_s_setprio(1);                                             \
    _Pragma("unroll")                                                          \
    for (int ks = 0; ks < 2; ++ks)                                             \
      _Pragma("unroll")                                                        \
      for (int n = 0; n < 4; ++n) {                                            \
        bf16x8 kf = ld_bf8(&lsK[((n * 16 + lr) * 64 + ks * 32 + lg * 8) ^ rsw]);\
        s[n] = __builtin_amdgcn_mfma_f32_16x16x32_bf16(qf[ks], kf, s[n], 0, 0, 0);\
      }                                                                        \
    __builtin_amdgcn_s_setprio(0);                                             \
    _Pragma("unroll")                                                          \
    for (int i = 0; i < 4; ++i) {                                              \
      float rs = 0.f;                                                          \
      _Pragma("unroll")                                                        \
      for (int n = 0; n < 4; ++n) {                                            \
        float p = __expf(s[n][i] + bbw[i][(NOFS) + n]);                        \
        s[n][i] = p;                                                           \
        rs += p;                                                               \
      }                                                                        \
      lsum[i] += rs;                                                           \
    }                                                                          \
    _Pragma("unroll")                                                          \
    for (int n = 0; n < 4; ++n)                                                \
      _Pragma("unroll")                                                        \
      for (int i = 0; i < 4; ++i)                                              \
        lsP[wid][(lg * 4 + i) * 88 + n * 16 + lr] = f2bf(s[n][i]);             \
    asm volatile("s_waitcnt lgkmcnt(0)" ::: "memory");                         \
    __builtin_amdgcn_sched_barrier(0);                                         \
    __builtin_amdgcn_s_setprio(1);                                             \
    _Pragma("unroll")                                                          \
    for (int ks = 0; ks < 2; ++ks) {                                           \
      bf16x8 pa = ld_bf8(&lsP[wid][lr * 88 + ks * 32 + lg * 8]);               \
      _Pragma("unroll")                                                        \
      for (int dt = 0; dt < 4; ++dt) {                                         \
        bf16x8 vf = ld_bf8(&lsV[((dt * 16 + lr) * 64 + ks * 32 + lg * 8) ^ rsw]);\
        o[dt] = __builtin_amdgcn_mfma_f32_16x16x32_bf16(pa, vf, o[dt], 0, 0, 0);\
      }                                                                        \
    }                                                                          \
    __builtin_amdgcn_s_setprio(0);                                             \
  }

  for (int kt2 = 0; kt2 < 16; ++kt2) {
    const int k0 = kt2 * 128;
    SUBITER(k0, 0, 1);        // even: stage + 512B-burst bias load (128 cols)
    SUBITER(k0 + 64, 4, 0);   // odd: stage only, consume held bias
  }
#undef SUBITER

  // epilogue: single 16-lane reduce of lsum partials, then write
#pragma unroll
  for (int i = 0; i < 4; ++i) {
    lsum[i] += __shfl_xor(lsum[i], 1);
    lsum[i] += __shfl_xor(lsum[i], 2);
    lsum[i] += __shfl_xor(lsum[i], 4);
    lsum[i] += __shfl_xor(lsum[i], 8);
  }
  float inv[4];
#pragma unroll
  for (int i = 0; i < 4; ++i) inv[i] = 1.0f / lsum[i];
#pragma unroll
  for (int dt = 0; dt < 4; ++dt) {
    const int dcol = h * 64 + dt * 16 + lr;
#pragma unroll
    for (int i = 0; i < 4; ++i)
      attn[((size_t)b * 2048 + qrow0 + i) * 1024 + dcol] = f2bf(o[dt][i] * inv[i]);
  }
}

// ---------------- launch ------------------------------------------------------
extern "C" void kernel_launch(void* const* d_in, const int* in_sizes, int n_in,
                              void* d_out, int out_size, void* d_ws, size_t ws_size,
                              hipStream_t stream) {
  const float* x    = (const float*)d_in[0];
  const float* bias = (const float*)d_in[1];
  const float* mask = (const float*)d_in[2];
  const float* Wq   = (const float*)d_in[3];
  const float* bq   = (const float*)d_in[4];
  const float* Wk   = (const float*)d_in[5];
  const float* bk   = (const float*)d_in[6];
  const float* Wv   = (const float*)d_in[7];
  const float* bv   = (const float*)d_in[8];
  const float* Wo   = (const float*)d_in[9];
  const float* bo   = (const float*)d_in[10];
  float* out = (float*)d_out;

  u16* ws   = (u16*)d_ws;
  u16* xb   = ws;                    // 4194304
  u16* wqb  = ws + 4194304L;         // 1048576
  u16* wkb  = wqb + 1048576L;
  u16* wvb  = wkb + 1048576L;
  u16* wob  = wvb + 1048576L;
  u16* Qb   = wob + 1048576L;        // 4194304 (B,H,L,HD)
  u16* Kb   = Qb + 4194304L;         // 4194304
  u16* Vtb  = Kb + 4194304L;         // 4194304 (B,H,HD,L)
  u16* attnb = Vtb + 4194304L;       // 4194304 (B,L,D)
  int* mzflag = (int*)(attnb + 4194304L);

  hipMemsetAsync(mzflag, 0, 4, stream);
  cvt_scan_kernel<<<8192, 256, 0, stream>>>(x, Wq, Wk, Wv, Wo, ws, mask, mzflag);

  dim3 gqkv(8, 32, 3);
  gemm_bt<<<gqkv, 256, 0, stream>>>(xb, wqb, wkb, wvb, bq, bk, bv,
                                    (void*)Qb, (void*)Kb, (void*)Vtb, 0);

  attn_kernel<<<dim3(1024), 256, 0, stream>>>(Qb, Kb, Vtb, bias, mask, mzflag, attnb);

  gemm_out64<<<dim3(8, 64), 256, 0, stream>>>(attnb, wob, bo, out);
}